// Round 18
// baseline (10440.876 us; speedup 1.0000x reference)
//
#include <hip/hip_runtime.h>
#include <math.h>

// ROUND 18: OUTPUT IS FP32 (world model closed: out_npz=31MiB=8.4M*4B; all
// "invisible spikes" were 2-byte writes into an fp32 buffer; bf16 field reads
// as spliced pairs -> the stable 7.218750). Pipeline = r13 (multiplicative
// boolean mask, fp64 scores, two-pass softmax) with FP32 output writes.
// ws per batch (24MB): QK f64 [CB*1024][2048] | V f32 [CB*1024][1024] |
//                      AO f32 [CB*1024][1024]

// ---------------- K1: QKV GEMM (fp64 accumulate, 8 rows/block) ----------------
__global__ __launch_bounds__(256) void qkv_k(
    const float* __restrict__ X, const float* __restrict__ W,
    const float* __restrict__ bias, double* __restrict__ QK,
    float* __restrict__ V, int b0)
{
  const int t = threadIdx.x;
  const int n = blockIdx.x * 256 + t;       // 0..3071
  const int m0 = blockIdx.y * 8;            // chunk-local row
  double acc[8] = {};
  const size_t grow0 = (size_t)b0 * 1024 + m0;
  for (int k = 0; k < 1024; ++k) {
    double w = (double)W[(size_t)k * 3072 + n];
#pragma unroll
    for (int r = 0; r < 8; ++r)
      acc[r] = fma((double)X[(grow0 + r) * 1024 + k], w, acc[r]);
  }
  double bz = (double)bias[n];
  if (n < 2048) {
#pragma unroll
    for (int r = 0; r < 8; ++r)
      QK[(size_t)(m0 + r) * 2048 + n] = acc[r] + bz;
  } else {
#pragma unroll
    for (int r = 0; r < 8; ++r)
      V[(size_t)(m0 + r) * 1024 + (n - 2048)] = (float)(acc[r] + bz);
  }
}

// ---------------- K2: attention (multiplicative mask, fp64 scores) ----------------
__global__ __launch_bounds__(256) void attn_k(
    const float* __restrict__ Mask, const double* __restrict__ QK,
    const float* __restrict__ V, float* __restrict__ AO, int b0)
{
  __shared__ double qd[64];
  __shared__ double zd[1024];
  __shared__ float  pp[1024];
  __shared__ double red[256];
  __shared__ float  op[4][64];
  const int t = threadIdx.x;
  const int q = blockIdx.x;            // 0..1023
  const int bh = blockIdx.y;           // chunk-local bh
  const int bl = bh >> 4, h = bh & 15;
  const int bg = b0 + bl;              // global batch

  if (t < 64) qd[t] = QK[(size_t)(bl * 1024 + q) * 2048 + h * 64 + t];
  __syncthreads();

  // z = (q.k/8)*(mask*-1e9): masked -> s*-1.25e8; unmasked -> 0
  for (int k = t; k < 1024; k += 256) {
    const double* kr = &QK[(size_t)(bl * 1024 + k) * 2048 + 1024 + h * 64];
    double s = 0.0;
    for (int d = 0; d < 64; ++d) s = fma(qd[d], kr[d], s);
    float mv = Mask[(size_t)bg * 1048576 + (size_t)q * 1024 + k];
    zd[k] = (mv != 0.f) ? s * -1.25e8 : 0.0;
  }
  __syncthreads();

  double mx = -1e300;
  for (int k = t; k < 1024; k += 256) mx = fmax(mx, zd[k]);
  red[t] = mx;
  __syncthreads();
  for (int s2 = 128; s2 > 0; s2 >>= 1) {
    if (t < s2) red[t] = fmax(red[t], red[t + s2]);
    __syncthreads();
  }
  const double M = red[0];
  __syncthreads();

  double ls = 0.0;
  for (int k = t; k < 1024; k += 256) {
    float p = expf((float)fmax(zd[k] - M, -200.0));
    pp[k] = p;
    ls += (double)p;
  }
  red[t] = ls;
  __syncthreads();
  for (int s2 = 128; s2 > 0; s2 >>= 1) {
    if (t < s2) red[t] = red[t] + red[t + s2];
    __syncthreads();
  }
  const float L = (float)red[0];

  const int d = t & 63, seg = t >> 6;
  float o = 0.f;
  for (int k = seg * 256; k < seg * 256 + 256; ++k)
    o = fmaf(pp[k], V[(size_t)(bl * 1024 + k) * 1024 + h * 64 + d], o);
  op[seg][d] = o;
  __syncthreads();
  if (t < 64) {
    float out = (op[0][t] + op[1][t] + op[2][t] + op[3][t]) / L;
    AO[(size_t)(bl * 1024 + q) * 1024 + h * 64 + t] = out;
  }
}

// ---------------- K3: output projection -> FP32 out ----------------
__global__ __launch_bounds__(256) void proj_k(
    const float* __restrict__ AO, const float* __restrict__ W,
    const float* __restrict__ bias, float* __restrict__ Out, int b0)
{
  const int t = threadIdx.x;
  const int n = blockIdx.x * 256 + t;   // 0..1023
  const int m0 = blockIdx.y * 8;        // chunk-local row
  float acc[8] = {};
  for (int k = 0; k < 1024; ++k) {
    float w = W[(size_t)k * 1024 + n];
#pragma unroll
    for (int r = 0; r < 8; ++r)
      acc[r] = fmaf(AO[(size_t)(m0 + r) * 1024 + k], w, acc[r]);
  }
  float bz = bias[n];
#pragma unroll
  for (int r = 0; r < 8; ++r)
    Out[((size_t)b0 * 1024 + m0 + r) * 1024 + n] = acc[r] + bz;
}

extern "C" void kernel_launch(void* const* d_in, const int* in_sizes, int n_in,
                              void* d_out, int out_size, void* d_ws, size_t ws_size,
                              hipStream_t stream) {
  (void)in_sizes; (void)n_in; (void)out_size;
  const float* x      = (const float*)d_in[0];
  const float* mask   = (const float*)d_in[1];
  const float* W_attn = (const float*)d_in[2];
  const float* b_attn = (const float*)d_in[3];
  const float* W_proj = (const float*)d_in[4];
  const float* b_proj = (const float*)d_in[5];
  float* out = (float*)d_out;

  int CB = (ws_size >= (192ull << 20)) ? 8
         : (ws_size >= (96ull  << 20)) ? 4
         : (ws_size >= (48ull  << 20)) ? 2 : 1;

  char* base = (char*)d_ws;
  double* QK = (double*)base;                                  // CB*16MB
  float*  V  = (float*)(base + (size_t)CB * (16ull << 20));    // CB*4MB
  float*  AO = (float*)(base + (size_t)CB * (20ull << 20));    // CB*4MB

  for (int b0 = 0; b0 < 8; b0 += CB) {
    qkv_k<<<dim3(12, CB * 128), 256, 0, stream>>>(x, W_attn, b_attn, QK, V, b0);
    attn_k<<<dim3(1024, CB * 16), 256, 0, stream>>>(mask, QK, V, AO, b0);
    proj_k<<<dim3(4, CB * 128), 256, 0, stream>>>(AO, W_proj, b_proj, out, b0);
  }
}

// Round 19
// 2563.376 us; speedup vs baseline: 4.0731x; 4.0731x over previous
//
#include <hip/hip_runtime.h>
#include <math.h>

// ROUND 19 (first optimization round after pass).
// Numerics IDENTICAL to r18's passing config: fp64 score path (q,k GEMM +
// QK^T), multiplicative boolean mask, online softmax w/ -80 cutoff (same
// fp32 outputs as two-pass), fp32 V/PV/proj, fp32 output.
// Implementation: tiled/LDS-staged kernels instead of naive.
// ws per batch (24MB): qT f64 [16h][64d][1024s] | kT same | V f32 [16h][1024s][64d]
//                      | AO f32 [1024][1024]

// ---------------- K1: q,k GEMM fp64, 64x64 tile, 4x4/thread ----------------
__global__ __launch_bounds__(256) void qk_gemm_f64(
    const float* __restrict__ X, const float* __restrict__ W,
    const float* __restrict__ bias,
    double* __restrict__ qT, double* __restrict__ kT, int b0)
{
  __shared__ double As[16][68];   // [kk][m]
  __shared__ double Bs[16][68];   // [kk][n]
  const int t = threadIdx.x, tx = t & 15, ty = t >> 4;
  const int n0 = blockIdx.x * 64;      // 0..2047 (q,k cols)
  const int m0 = blockIdx.y * 64;      // chunk-local row
  double acc[4][4] = {};
  const size_t xrow0 = (size_t)b0 * 1024 + m0;

  for (int k0 = 0; k0 < 1024; k0 += 16) {
    __syncthreads();
    {
      int r = t >> 2, kq = (t & 3) << 2;
      float4 xv = *(const float4*)&X[(xrow0 + r) * 1024 + k0 + kq];
      As[kq + 0][r] = (double)xv.x;
      As[kq + 1][r] = (double)xv.y;
      As[kq + 2][r] = (double)xv.z;
      As[kq + 3][r] = (double)xv.w;
      int kr = t >> 4, cq = (t & 15) << 2;
      float4 wv = *(const float4*)&W[(size_t)(k0 + kr) * 3072 + n0 + cq];
      Bs[kr][cq + 0] = (double)wv.x;
      Bs[kr][cq + 1] = (double)wv.y;
      Bs[kr][cq + 2] = (double)wv.z;
      Bs[kr][cq + 3] = (double)wv.w;
    }
    __syncthreads();
#pragma unroll
    for (int kk = 0; kk < 16; ++kk) {
      double a0 = As[kk][4 * ty + 0], a1 = As[kk][4 * ty + 1];
      double a2 = As[kk][4 * ty + 2], a3 = As[kk][4 * ty + 3];
      double c0 = Bs[kk][4 * tx + 0], c1 = Bs[kk][4 * tx + 1];
      double c2 = Bs[kk][4 * tx + 2], c3 = Bs[kk][4 * tx + 3];
      acc[0][0] = fma(a0, c0, acc[0][0]); acc[0][1] = fma(a0, c1, acc[0][1]);
      acc[0][2] = fma(a0, c2, acc[0][2]); acc[0][3] = fma(a0, c3, acc[0][3]);
      acc[1][0] = fma(a1, c0, acc[1][0]); acc[1][1] = fma(a1, c1, acc[1][1]);
      acc[1][2] = fma(a1, c2, acc[1][2]); acc[1][3] = fma(a1, c3, acc[1][3]);
      acc[2][0] = fma(a2, c0, acc[2][0]); acc[2][1] = fma(a2, c1, acc[2][1]);
      acc[2][2] = fma(a2, c2, acc[2][2]); acc[2][3] = fma(a2, c3, acc[2][3]);
      acc[3][0] = fma(a3, c0, acc[3][0]); acc[3][1] = fma(a3, c1, acc[3][1]);
      acc[3][2] = fma(a3, c2, acc[3][2]); acc[3][3] = fma(a3, c3, acc[3][3]);
    }
  }
  double* T = (n0 < 1024) ? qT : kT;
  const int nn = n0 & 1023;
  const int h = nn >> 6;              // 64-wide tile = one head
  const int bl = m0 >> 10;
  const int sb = m0 & 1023;
  const size_t hb = (size_t)(bl * 16 + h) * 64;
#pragma unroll
  for (int j = 0; j < 4; ++j) {
    double bz = (double)bias[n0 + 4 * tx + j];
    size_t sidx = ((hb + 4 * tx + j) << 10) + sb + 4 * ty;
    *(double2*)&T[sidx]     = make_double2(acc[0][j] + bz, acc[1][j] + bz);
    *(double2*)&T[sidx + 2] = make_double2(acc[2][j] + bz, acc[3][j] + bz);
  }
}

// ---------------- K2: v GEMM fp32, 128x128 tile ----------------
__global__ __launch_bounds__(256) void v_gemm_f32(
    const float* __restrict__ X, const float* __restrict__ W,
    const float* __restrict__ bias, float* __restrict__ Vp, int b0)
{
  __shared__ __align__(16) float As[16][132];
  __shared__ __align__(16) float Bs[16][132];
  const int t = threadIdx.x, tx = t & 15, ty = t >> 4;
  const int n0 = blockIdx.x * 128;     // 0..1023 (v cols)
  const int m0 = blockIdx.y * 128;     // chunk-local row
  float acc[2][2][4][4] = {};
  const size_t xrow0 = (size_t)b0 * 1024 + m0;

  for (int k0 = 0; k0 < 1024; k0 += 16) {
    __syncthreads();
#pragma unroll
    for (int p = 0; p < 2; ++p) {
      int f = p * 256 + t;
      int r = f >> 2, kq = (f & 3) << 2;
      float4 xv = *(const float4*)&X[(xrow0 + r) * 1024 + k0 + kq];
      As[kq + 0][r] = xv.x; As[kq + 1][r] = xv.y;
      As[kq + 2][r] = xv.z; As[kq + 3][r] = xv.w;
      int kr = f >> 5, cq = (f & 31) << 2;
      *(float4*)&Bs[kr][cq] = *(const float4*)&W[(size_t)(k0 + kr) * 3072 + 2048 + n0 + cq];
    }
    __syncthreads();
#pragma unroll
    for (int kk = 0; kk < 16; ++kk) {
      float4 A0 = *(const float4*)&As[kk][4 * ty];
      float4 A1 = *(const float4*)&As[kk][64 + 4 * ty];
      float4 B0 = *(const float4*)&Bs[kk][4 * tx];
      float4 B1 = *(const float4*)&Bs[kk][64 + 4 * tx];
      float a[2][4] = {{A0.x, A0.y, A0.z, A0.w}, {A1.x, A1.y, A1.z, A1.w}};
      float b[2][4] = {{B0.x, B0.y, B0.z, B0.w}, {B1.x, B1.y, B1.z, B1.w}};
#pragma unroll
      for (int ri = 0; ri < 2; ++ri)
#pragma unroll
        for (int i = 0; i < 4; ++i)
#pragma unroll
          for (int ci = 0; ci < 2; ++ci)
#pragma unroll
            for (int j = 0; j < 4; ++j)
              acc[ri][ci][i][j] = fmaf(a[ri][i], b[ci][j], acc[ri][ci][i][j]);
    }
  }
  const int bl = m0 >> 10;
  const int sb = m0 & 1023;
#pragma unroll
  for (int ci = 0; ci < 2; ++ci) {
    int h = (n0 >> 6) + ci;
    float bz[4];
#pragma unroll
    for (int j = 0; j < 4; ++j) bz[j] = bias[2048 + n0 + 64 * ci + 4 * tx + j];
#pragma unroll
    for (int ri = 0; ri < 2; ++ri)
#pragma unroll
      for (int i = 0; i < 4; ++i) {
        int s = sb + 64 * ri + 4 * ty + i;
        float4 vv = make_float4(acc[ri][ci][i][0] + bz[0], acc[ri][ci][i][1] + bz[1],
                                acc[ri][ci][i][2] + bz[2], acc[ri][ci][i][3] + bz[3]);
        *(float4*)&Vp[((size_t)(bl * 16 + h) * 1024 + s) * 64 + 4 * tx] = vv;
      }
  }
}

// ---------------- K3: fused attention, fp64 scores, online softmax ----------------
// 128 threads: tx=t&15 (k cols 4tx+j), ty=t>>4 in 0..7 (q rows 4ty+i). q-block 32.
__global__ __launch_bounds__(128) void attn_fused(
    const double* __restrict__ qT, const double* __restrict__ kT,
    const float* __restrict__ Vp, const float* __restrict__ Mask,
    float* __restrict__ AO, int b0)
{
  __shared__ double Qs[64][34];    // [d][q]
  __shared__ double KV[64][68];    // K [d][k] f64; V phase reuses as fp32 flat
  __shared__ float  Ps[32][68];    // [q][k]
  const int t = threadIdx.x, tx = t & 15, ty = t >> 4;
  const int bh = blockIdx.y;       // chunk-local bh
  const int bl = bh >> 4, h = bh & 15;
  const int bg = b0 + bl;          // global batch (mask)
  const int q0 = blockIdx.x * 32;
  const double* qTb = qT + (size_t)bh * 64 * 1024;
  const double* kTb = kT + (size_t)bh * 64 * 1024;
  const float*  Vb  = Vp + (size_t)bh * 1024 * 64;
  const float*  mb  = Mask + (size_t)bg * 1048576 + (size_t)q0 * 1024;
  float* Vf = (float*)&KV[0][0];

#pragma unroll
  for (int p = 0; p < 16; ++p) {
    int f = p * 128 + t;
    Qs[f >> 5][f & 31] = qTb[(size_t)(f >> 5) * 1024 + q0 + (f & 31)];
  }

  double Mreg[4] = {-1e300, -1e300, -1e300, -1e300};
  float Lreg[4] = {0.f, 0.f, 0.f, 0.f};
  float o[4][4] = {};

  for (int kt = 0; kt < 16; ++kt) {
    const int k0 = kt * 64;
    __syncthreads();                    // A: prev PV reads of KV/Ps done
#pragma unroll
    for (int p = 0; p < 32; ++p) {
      int f = p * 128 + t;
      KV[f >> 6][f & 63] = kTb[(size_t)(f >> 6) * 1024 + k0 + (f & 63)];
    }
    __syncthreads();                    // B: K staged
    double s[4][4] = {};
#pragma unroll 8
    for (int d = 0; d < 64; ++d) {
      double2 qa = *(const double2*)&Qs[d][4 * ty];
      double2 qb = *(const double2*)&Qs[d][4 * ty + 2];
      double2 ka = *(const double2*)&KV[d][4 * tx];
      double2 kb = *(const double2*)&KV[d][4 * tx + 2];
      double aq[4] = {qa.x, qa.y, qb.x, qb.y};
      double ak[4] = {ka.x, ka.y, kb.x, kb.y};
#pragma unroll
      for (int i = 0; i < 4; ++i)
#pragma unroll
        for (int j = 0; j < 4; ++j)
          s[i][j] = fma(aq[i], ak[j], s[i][j]);
    }
    float al[4];
#pragma unroll
    for (int i = 0; i < 4; ++i) {
      const int q = 4 * ty + i;
      float4 mv = *(const float4*)&mb[(size_t)q * 1024 + k0 + 4 * tx];
      // z = (q.k/8)*(mask*-1e9): masked -> s*-1.25e8 (single rounding); else 0
      double z0 = (mv.x != 0.f) ? s[i][0] * -1.25e8 : 0.0;
      double z1 = (mv.y != 0.f) ? s[i][1] * -1.25e8 : 0.0;
      double z2 = (mv.z != 0.f) ? s[i][2] * -1.25e8 : 0.0;
      double z3 = (mv.w != 0.f) ? s[i][3] * -1.25e8 : 0.0;
      double mx = fmax(fmax(z0, z1), fmax(z2, z3));
#pragma unroll
      for (int w = 1; w < 16; w <<= 1) mx = fmax(mx, __shfl_xor(mx, w));
      double nM = fmax(Mreg[i], mx);
      double da = Mreg[i] - nM;
      al[i] = (da < -80.0) ? 0.f : expf((float)da);
      double d0 = z0 - nM, d1 = z1 - nM, d2 = z2 - nM, d3 = z3 - nM;
      float p0 = (d0 < -80.0) ? 0.f : expf((float)d0);
      float p1 = (d1 < -80.0) ? 0.f : expf((float)d1);
      float p2 = (d2 < -80.0) ? 0.f : expf((float)d2);
      float p3 = (d3 < -80.0) ? 0.f : expf((float)d3);
      float ps = ((p0 + p1) + p2) + p3;
#pragma unroll
      for (int w = 1; w < 16; w <<= 1) ps += __shfl_xor(ps, w);
      Lreg[i] = Lreg[i] * al[i] + ps;
      Mreg[i] = nM;
      *(float4*)&Ps[q][4 * tx] = make_float4(p0, p1, p2, p3);
    }
    __syncthreads();                    // C: KV reads done, Ps written
#pragma unroll
    for (int p = 0; p < 8; ++p) {
      int f = p * 128 + t;
      *(float4*)&Vf[4 * f] = *(const float4*)&Vb[(size_t)k0 * 64 + 4 * f];
    }
    __syncthreads();                    // D: V staged
#pragma unroll
    for (int i = 0; i < 4; ++i) {
      o[i][0] *= al[i]; o[i][1] *= al[i]; o[i][2] *= al[i]; o[i][3] *= al[i];
    }
#pragma unroll 8
    for (int kk = 0; kk < 64; ++kk) {
      float4 vv = *(const float4*)&Vf[kk * 64 + 4 * tx];
#pragma unroll
      for (int i = 0; i < 4; ++i) {
        float pp = Ps[4 * ty + i][kk];
        o[i][0] = fmaf(pp, vv.x, o[i][0]);
        o[i][1] = fmaf(pp, vv.y, o[i][1]);
        o[i][2] = fmaf(pp, vv.z, o[i][2]);
        o[i][3] = fmaf(pp, vv.w, o[i][3]);
      }
    }
  }
#pragma unroll
  for (int i = 0; i < 4; ++i) {
    const int q = 4 * ty + i;
    float inv = (Lreg[i] > 0.f) ? 1.f / Lreg[i] : 0.f;
    float4 vv = make_float4(o[i][0] * inv, o[i][1] * inv, o[i][2] * inv, o[i][3] * inv);
    *(float4*)&AO[(size_t)(bl * 1024 + q0 + q) * 1024 + h * 64 + 4 * tx] = vv;
  }
}

// ---------------- K4: output projection fp32, 128x128 tile -> FP32 out ----------------
__global__ __launch_bounds__(256) void proj_gemm(
    const float* __restrict__ AO, const float* __restrict__ W,
    const float* __restrict__ bias, float* __restrict__ Out, int b0)
{
  __shared__ __align__(16) float As[16][132];
  __shared__ __align__(16) float Bs[16][132];
  const int t = threadIdx.x, tx = t & 15, ty = t >> 4;
  const int n0 = blockIdx.x * 128;
  const int m0l = blockIdx.y * 128;    // chunk-local row
  float acc[2][2][4][4] = {};

  for (int k0 = 0; k0 < 1024; k0 += 16) {
    __syncthreads();
#pragma unroll
    for (int p = 0; p < 2; ++p) {
      int f = p * 256 + t;
      int r = f >> 2, kq = (f & 3) << 2;
      float4 av = *(const float4*)&AO[(size_t)(m0l + r) * 1024 + k0 + kq];
      As[kq + 0][r] = av.x; As[kq + 1][r] = av.y;
      As[kq + 2][r] = av.z; As[kq + 3][r] = av.w;
      int kr = f >> 5, cq = (f & 31) << 2;
      *(float4*)&Bs[kr][cq] = *(const float4*)&W[(size_t)(k0 + kr) * 1024 + n0 + cq];
    }
    __syncthreads();
#pragma unroll
    for (int kk = 0; kk < 16; ++kk) {
      float4 A0 = *(const float4*)&As[kk][4 * ty];
      float4 A1 = *(const float4*)&As[kk][64 + 4 * ty];
      float4 B0 = *(const float4*)&Bs[kk][4 * tx];
      float4 B1 = *(const float4*)&Bs[kk][64 + 4 * tx];
      float a[2][4] = {{A0.x, A0.y, A0.z, A0.w}, {A1.x, A1.y, A1.z, A1.w}};
      float b[2][4] = {{B0.x, B0.y, B0.z, B0.w}, {B1.x, B1.y, B1.z, B1.w}};
#pragma unroll
      for (int ri = 0; ri < 2; ++ri)
#pragma unroll
        for (int i = 0; i < 4; ++i)
#pragma unroll
          for (int ci = 0; ci < 2; ++ci)
#pragma unroll
            for (int j = 0; j < 4; ++j)
              acc[ri][ci][i][j] = fmaf(a[ri][i], b[ci][j], acc[ri][ci][i][j]);
    }
  }
#pragma unroll
  for (int ci = 0; ci < 2; ++ci) {
    float bz[4];
#pragma unroll
    for (int j = 0; j < 4; ++j) bz[j] = bias[n0 + 64 * ci + 4 * tx + j];
#pragma unroll
    for (int ri = 0; ri < 2; ++ri)
#pragma unroll
      for (int i = 0; i < 4; ++i) {
        float4 vv = make_float4(acc[ri][ci][i][0] + bz[0], acc[ri][ci][i][1] + bz[1],
                                acc[ri][ci][i][2] + bz[2], acc[ri][ci][i][3] + bz[3]);
        size_t row = (size_t)b0 * 1024 + m0l + 64 * ri + 4 * ty + i;
        *(float4*)&Out[row * 1024 + n0 + 64 * ci + 4 * tx] = vv;
      }
  }
}

extern "C" void kernel_launch(void* const* d_in, const int* in_sizes, int n_in,
                              void* d_out, int out_size, void* d_ws, size_t ws_size,
                              hipStream_t stream) {
  (void)in_sizes; (void)n_in; (void)out_size;
  const float* x      = (const float*)d_in[0];
  const float* mask   = (const float*)d_in[1];
  const float* W_attn = (const float*)d_in[2];
  const float* b_attn = (const float*)d_in[3];
  const float* W_proj = (const float*)d_in[4];
  const float* b_proj = (const float*)d_in[5];
  float* out = (float*)d_out;

  int CB = (ws_size >= (192ull << 20)) ? 8
         : (ws_size >= (96ull  << 20)) ? 4
         : (ws_size >= (48ull  << 20)) ? 2 : 1;

  char* base = (char*)d_ws;
  double* qT = (double*)base;                                  // CB*8MB
  double* kT = (double*)(base + (size_t)CB * (8ull  << 20));   // CB*8MB
  float*  Vp = (float*)(base + (size_t)CB * (16ull << 20));    // CB*4MB
  float*  AO = (float*)(base + (size_t)CB * (20ull << 20));    // CB*4MB

  for (int b0 = 0; b0 < 8; b0 += CB) {
    qk_gemm_f64<<<dim3(32, 16 * CB), 256, 0, stream>>>(x, W_attn, b_attn, qT, kT, b0);
    v_gemm_f32<<<dim3(8, 8 * CB), 256, 0, stream>>>(x, W_attn, b_attn, Vp, b0);
    attn_fused<<<dim3(32, 16 * CB), 128, 0, stream>>>(qT, kT, Vp, mask, AO, b0);
    proj_gemm<<<dim3(8, 8 * CB), 256, 0, stream>>>(AO, W_proj, b_proj, out, b0);
  }
}

// Round 20
// 2078.392 us; speedup vs baseline: 5.0235x; 1.2333x over previous
//
#include <hip/hip_runtime.h>
#include <math.h>

// ROUND 20: attn_fused rework — 256 thr, q-block 64, LDS aliasing (K buffer
// reused for Ps+V after S-phase) -> 64KB LDS, 2 blocks/CU, 2 waves/SIMD
// (was 1). Paired q/k lane assignment keeps all LDS reads <=2-way (free).
// Score numerics bit-identical to r19 (fp64 d-ascending FMA, same mask/exp
// formulas, PV kk-ascending). qk_gemm/v_gemm/proj unchanged from r19.

// ---------------- K1: q,k GEMM fp64, 64x64 tile, 4x4/thread ----------------
__global__ __launch_bounds__(256) void qk_gemm_f64(
    const float* __restrict__ X, const float* __restrict__ W,
    const float* __restrict__ bias,
    double* __restrict__ qT, double* __restrict__ kT, int b0)
{
  __shared__ double As[16][68];   // [kk][m]
  __shared__ double Bs[16][68];   // [kk][n]
  const int t = threadIdx.x, tx = t & 15, ty = t >> 4;
  const int n0 = blockIdx.x * 64;      // 0..2047 (q,k cols)
  const int m0 = blockIdx.y * 64;      // chunk-local row
  double acc[4][4] = {};
  const size_t xrow0 = (size_t)b0 * 1024 + m0;

  for (int k0 = 0; k0 < 1024; k0 += 16) {
    __syncthreads();
    {
      int r = t >> 2, kq = (t & 3) << 2;
      float4 xv = *(const float4*)&X[(xrow0 + r) * 1024 + k0 + kq];
      As[kq + 0][r] = (double)xv.x;
      As[kq + 1][r] = (double)xv.y;
      As[kq + 2][r] = (double)xv.z;
      As[kq + 3][r] = (double)xv.w;
      int kr = t >> 4, cq = (t & 15) << 2;
      float4 wv = *(const float4*)&W[(size_t)(k0 + kr) * 3072 + n0 + cq];
      Bs[kr][cq + 0] = (double)wv.x;
      Bs[kr][cq + 1] = (double)wv.y;
      Bs[kr][cq + 2] = (double)wv.z;
      Bs[kr][cq + 3] = (double)wv.w;
    }
    __syncthreads();
#pragma unroll
    for (int kk = 0; kk < 16; ++kk) {
      double a0 = As[kk][4 * ty + 0], a1 = As[kk][4 * ty + 1];
      double a2 = As[kk][4 * ty + 2], a3 = As[kk][4 * ty + 3];
      double c0 = Bs[kk][4 * tx + 0], c1 = Bs[kk][4 * tx + 1];
      double c2 = Bs[kk][4 * tx + 2], c3 = Bs[kk][4 * tx + 3];
      acc[0][0] = fma(a0, c0, acc[0][0]); acc[0][1] = fma(a0, c1, acc[0][1]);
      acc[0][2] = fma(a0, c2, acc[0][2]); acc[0][3] = fma(a0, c3, acc[0][3]);
      acc[1][0] = fma(a1, c0, acc[1][0]); acc[1][1] = fma(a1, c1, acc[1][1]);
      acc[1][2] = fma(a1, c2, acc[1][2]); acc[1][3] = fma(a1, c3, acc[1][3]);
      acc[2][0] = fma(a2, c0, acc[2][0]); acc[2][1] = fma(a2, c1, acc[2][1]);
      acc[2][2] = fma(a2, c2, acc[2][2]); acc[2][3] = fma(a2, c3, acc[2][3]);
      acc[3][0] = fma(a3, c0, acc[3][0]); acc[3][1] = fma(a3, c1, acc[3][1]);
      acc[3][2] = fma(a3, c2, acc[3][2]); acc[3][3] = fma(a3, c3, acc[3][3]);
    }
  }
  double* T = (n0 < 1024) ? qT : kT;
  const int nn = n0 & 1023;
  const int h = nn >> 6;              // 64-wide tile = one head
  const int bl = m0 >> 10;
  const int sb = m0 & 1023;
  const size_t hb = (size_t)(bl * 16 + h) * 64;
#pragma unroll
  for (int j = 0; j < 4; ++j) {
    double bz = (double)bias[n0 + 4 * tx + j];
    size_t sidx = ((hb + 4 * tx + j) << 10) + sb + 4 * ty;
    *(double2*)&T[sidx]     = make_double2(acc[0][j] + bz, acc[1][j] + bz);
    *(double2*)&T[sidx + 2] = make_double2(acc[2][j] + bz, acc[3][j] + bz);
  }
}

// ---------------- K2: v GEMM fp32, 128x128 tile ----------------
__global__ __launch_bounds__(256) void v_gemm_f32(
    const float* __restrict__ X, const float* __restrict__ W,
    const float* __restrict__ bias, float* __restrict__ Vp, int b0)
{
  __shared__ __align__(16) float As[16][132];
  __shared__ __align__(16) float Bs[16][132];
  const int t = threadIdx.x, tx = t & 15, ty = t >> 4;
  const int n0 = blockIdx.x * 128;     // 0..1023 (v cols)
  const int m0 = blockIdx.y * 128;     // chunk-local row
  float acc[2][2][4][4] = {};
  const size_t xrow0 = (size_t)b0 * 1024 + m0;

  for (int k0 = 0; k0 < 1024; k0 += 16) {
    __syncthreads();
#pragma unroll
    for (int p = 0; p < 2; ++p) {
      int f = p * 256 + t;
      int r = f >> 2, kq = (f & 3) << 2;
      float4 xv = *(const float4*)&X[(xrow0 + r) * 1024 + k0 + kq];
      As[kq + 0][r] = xv.x; As[kq + 1][r] = xv.y;
      As[kq + 2][r] = xv.z; As[kq + 3][r] = xv.w;
      int kr = f >> 5, cq = (f & 31) << 2;
      *(float4*)&Bs[kr][cq] = *(const float4*)&W[(size_t)(k0 + kr) * 3072 + 2048 + n0 + cq];
    }
    __syncthreads();
#pragma unroll
    for (int kk = 0; kk < 16; ++kk) {
      float4 A0 = *(const float4*)&As[kk][4 * ty];
      float4 A1 = *(const float4*)&As[kk][64 + 4 * ty];
      float4 B0 = *(const float4*)&Bs[kk][4 * tx];
      float4 B1 = *(const float4*)&Bs[kk][64 + 4 * tx];
      float a[2][4] = {{A0.x, A0.y, A0.z, A0.w}, {A1.x, A1.y, A1.z, A1.w}};
      float b[2][4] = {{B0.x, B0.y, B0.z, B0.w}, {B1.x, B1.y, B1.z, B1.w}};
#pragma unroll
      for (int ri = 0; ri < 2; ++ri)
#pragma unroll
        for (int i = 0; i < 4; ++i)
#pragma unroll
          for (int ci = 0; ci < 2; ++ci)
#pragma unroll
            for (int j = 0; j < 4; ++j)
              acc[ri][ci][i][j] = fmaf(a[ri][i], b[ci][j], acc[ri][ci][i][j]);
    }
  }
  const int bl = m0 >> 10;
  const int sb = m0 & 1023;
#pragma unroll
  for (int ci = 0; ci < 2; ++ci) {
    int h = (n0 >> 6) + ci;
    float bz[4];
#pragma unroll
    for (int j = 0; j < 4; ++j) bz[j] = bias[2048 + n0 + 64 * ci + 4 * tx + j];
#pragma unroll
    for (int ri = 0; ri < 2; ++ri)
#pragma unroll
      for (int i = 0; i < 4; ++i) {
        int s = sb + 64 * ri + 4 * ty + i;
        float4 vv = make_float4(acc[ri][ci][i][0] + bz[0], acc[ri][ci][i][1] + bz[1],
                                acc[ri][ci][i][2] + bz[2], acc[ri][ci][i][3] + bz[3]);
        *(float4*)&Vp[((size_t)(bl * 16 + h) * 1024 + s) * 64 + 4 * tx] = vv;
      }
  }
}

// ---------------- K3: fused attention v2 ----------------
// 256 threads, q-block 64, k-tile 64. tx=t&15, ty=t>>4 (0..15).
// Thread owns q in {2ty,2ty+1,2ty+32,2ty+33}, k in {2tx,2tx+1,2tx+32,2tx+33}.
// LDS: Qs[64d][64q] f64 (32KB) + KVd[64d][64k] f64 (32KB); after S-phase the
// KVd region is reused as Ps[64q][64k] f32 (16KB) + Vf[64k][64d] f32 (16KB).
__global__ __launch_bounds__(256) void attn_fused(
    const double* __restrict__ qT, const double* __restrict__ kT,
    const float* __restrict__ Vp, const float* __restrict__ Mask,
    float* __restrict__ AO, int b0)
{
  __shared__ double Qs[64][64];
  __shared__ double KVd[64][64];
  const int t = threadIdx.x, tx = t & 15, ty = t >> 4;
  const int bh = blockIdx.y;       // chunk-local bh
  const int bl = bh >> 4, h = bh & 15;
  const int bg = b0 + bl;          // global batch (mask)
  const int q0 = blockIdx.x * 64;
  const double* qTb = qT + (size_t)bh * 65536;
  const double* kTb = kT + (size_t)bh * 65536;
  const float*  Vb  = Vp + (size_t)bh * 65536;
  const float*  mb  = Mask + (size_t)bg * 1048576 + (size_t)q0 * 1024;
  float* Ps = (float*)&KVd[0][0];                       // [64][64] f32
  float* Vf = (float*)((char*)&KVd[0][0] + 16384);      // [64][64] f32

  // stage Q [d][q]: 4096 doubles, 8 double2/thread
#pragma unroll
  for (int p = 0; p < 8; ++p) {
    int f = p * 256 + t;
    int d = f >> 5, c = f & 31;
    *(double2*)&Qs[d][2 * c] = *(const double2*)&qTb[(size_t)d * 1024 + q0 + 2 * c];
  }

  double Mreg[4] = {-1e300, -1e300, -1e300, -1e300};
  float Lreg[4] = {0.f, 0.f, 0.f, 0.f};
  float o[4][4] = {};

  for (int kt = 0; kt < 16; ++kt) {
    const int k0 = kt * 64;
    __syncthreads();                    // A: prev PV reads of Ps/Vf done (iter0: Q staged)
    // stage K [d][k]
#pragma unroll
    for (int p = 0; p < 8; ++p) {
      int f = p * 256 + t;
      int d = f >> 5, c = f & 31;
      *(double2*)&KVd[d][2 * c] = *(const double2*)&kTb[(size_t)d * 1024 + k0 + 2 * c];
    }
    __syncthreads();                    // B: K staged
    double s[4][4] = {};
#pragma unroll 4
    for (int d = 0; d < 64; ++d) {
      double2 qa = *(const double2*)&Qs[d][2 * ty];
      double2 qb = *(const double2*)&Qs[d][2 * ty + 32];
      double2 ka = *(const double2*)&KVd[d][2 * tx];
      double2 kb = *(const double2*)&KVd[d][2 * tx + 32];
      double aq[4] = {qa.x, qa.y, qb.x, qb.y};
      double ak[4] = {ka.x, ka.y, kb.x, kb.y};
#pragma unroll
      for (int i = 0; i < 4; ++i)
#pragma unroll
        for (int j = 0; j < 4; ++j)
          s[i][j] = fma(aq[i], ak[j], s[i][j]);
    }
    __syncthreads();                    // C: all KVd reads done -> region reusable
    float al[4];
#pragma unroll
    for (int i = 0; i < 4; ++i) {
      const int qi = 2 * ty + (i & 1) + (i >> 1) * 32;
      float2 m01 = *(const float2*)&mb[(size_t)qi * 1024 + k0 + 2 * tx];
      float2 m23 = *(const float2*)&mb[(size_t)qi * 1024 + k0 + 2 * tx + 32];
      // z = (q.k/8)*(mask*-1e9): masked -> s*-1.25e8 (single rounding); else 0
      double z0 = (m01.x != 0.f) ? s[i][0] * -1.25e8 : 0.0;
      double z1 = (m01.y != 0.f) ? s[i][1] * -1.25e8 : 0.0;
      double z2 = (m23.x != 0.f) ? s[i][2] * -1.25e8 : 0.0;
      double z3 = (m23.y != 0.f) ? s[i][3] * -1.25e8 : 0.0;
      double mx = fmax(fmax(z0, z1), fmax(z2, z3));
#pragma unroll
      for (int w = 1; w < 16; w <<= 1) mx = fmax(mx, __shfl_xor(mx, w));
      double nM = fmax(Mreg[i], mx);
      double da = Mreg[i] - nM;
      al[i] = (da < -80.0) ? 0.f : expf((float)da);
      double d0 = z0 - nM, d1 = z1 - nM, d2 = z2 - nM, d3 = z3 - nM;
      float p0 = (d0 < -80.0) ? 0.f : expf((float)d0);
      float p1 = (d1 < -80.0) ? 0.f : expf((float)d1);
      float p2 = (d2 < -80.0) ? 0.f : expf((float)d2);
      float p3 = (d3 < -80.0) ? 0.f : expf((float)d3);
      float ps = ((p0 + p1) + p2) + p3;
#pragma unroll
      for (int w = 1; w < 16; w <<= 1) ps += __shfl_xor(ps, w);
      Lreg[i] = Lreg[i] * al[i] + ps;
      Mreg[i] = nM;
      *(float2*)&Ps[qi * 64 + 2 * tx] = make_float2(p0, p1);
      *(float2*)&Ps[qi * 64 + 2 * tx + 32] = make_float2(p2, p3);
    }
    // stage V [k][d] into second half of reused region
#pragma unroll
    for (int p = 0; p < 4; ++p) {
      int f = p * 256 + t;
      *(float4*)&Vf[4 * f] = *(const float4*)&Vb[(size_t)k0 * 64 + 4 * f];
    }
    __syncthreads();                    // D: Ps + V ready
#pragma unroll
    for (int i = 0; i < 4; ++i) {
      o[i][0] *= al[i]; o[i][1] *= al[i]; o[i][2] *= al[i]; o[i][3] *= al[i];
    }
#pragma unroll 4
    for (int kk = 0; kk < 64; kk += 4) {
      float4 vv0 = *(const float4*)&Vf[(kk + 0) * 64 + 4 * tx];
      float4 vv1 = *(const float4*)&Vf[(kk + 1) * 64 + 4 * tx];
      float4 vv2 = *(const float4*)&Vf[(kk + 2) * 64 + 4 * tx];
      float4 vv3 = *(const float4*)&Vf[(kk + 3) * 64 + 4 * tx];
#pragma unroll
      for (int i = 0; i < 4; ++i) {
        const int qi = 2 * ty + (i & 1) + (i >> 1) * 32;
        float4 pa = *(const float4*)&Ps[qi * 64 + kk];
        o[i][0] = fmaf(pa.x, vv0.x, o[i][0]);
        o[i][0] = fmaf(pa.y, vv1.x, o[i][0]);
        o[i][0] = fmaf(pa.z, vv2.x, o[i][0]);
        o[i][0] = fmaf(pa.w, vv3.x, o[i][0]);
        o[i][1] = fmaf(pa.x, vv0.y, o[i][1]);
        o[i][1] = fmaf(pa.y, vv1.y, o[i][1]);
        o[i][1] = fmaf(pa.z, vv2.y, o[i][1]);
        o[i][1] = fmaf(pa.w, vv3.y, o[i][1]);
        o[i][2] = fmaf(pa.x, vv0.z, o[i][2]);
        o[i][2] = fmaf(pa.y, vv1.z, o[i][2]);
        o[i][2] = fmaf(pa.z, vv2.z, o[i][2]);
        o[i][2] = fmaf(pa.w, vv3.z, o[i][2]);
        o[i][3] = fmaf(pa.x, vv0.w, o[i][3]);
        o[i][3] = fmaf(pa.y, vv1.w, o[i][3]);
        o[i][3] = fmaf(pa.z, vv2.w, o[i][3]);
        o[i][3] = fmaf(pa.w, vv3.w, o[i][3]);
      }
    }
  }
#pragma unroll
  for (int i = 0; i < 4; ++i) {
    const int qi = 2 * ty + (i & 1) + (i >> 1) * 32;
    float inv = (Lreg[i] > 0.f) ? 1.f / Lreg[i] : 0.f;
    float4 vv = make_float4(o[i][0] * inv, o[i][1] * inv, o[i][2] * inv, o[i][3] * inv);
    *(float4*)&AO[(size_t)(bl * 1024 + q0 + qi) * 1024 + h * 64 + 4 * tx] = vv;
  }
}

// ---------------- K4: output projection fp32, 128x128 tile -> FP32 out ----------------
__global__ __launch_bounds__(256) void proj_gemm(
    const float* __restrict__ AO, const float* __restrict__ W,
    const float* __restrict__ bias, float* __restrict__ Out, int b0)
{
  __shared__ __align__(16) float As[16][132];
  __shared__ __align__(16) float Bs[16][132];
  const int t = threadIdx.x, tx = t & 15, ty = t >> 4;
  const int n0 = blockIdx.x * 128;
  const int m0l = blockIdx.y * 128;    // chunk-local row
  float acc[2][2][4][4] = {};

  for (int k0 = 0; k0 < 1024; k0 += 16) {
    __syncthreads();
#pragma unroll
    for (int p = 0; p < 2; ++p) {
      int f = p * 256 + t;
      int r = f >> 2, kq = (f & 3) << 2;
      float4 av = *(const float4*)&AO[(size_t)(m0l + r) * 1024 + k0 + kq];
      As[kq + 0][r] = av.x; As[kq + 1][r] = av.y;
      As[kq + 2][r] = av.z; As[kq + 3][r] = av.w;
      int kr = f >> 5, cq = (f & 31) << 2;
      *(float4*)&Bs[kr][cq] = *(const float4*)&W[(size_t)(k0 + kr) * 1024 + n0 + cq];
    }
    __syncthreads();
#pragma unroll
    for (int kk = 0; kk < 16; ++kk) {
      float4 A0 = *(const float4*)&As[kk][4 * ty];
      float4 A1 = *(const float4*)&As[kk][64 + 4 * ty];
      float4 B0 = *(const float4*)&Bs[kk][4 * tx];
      float4 B1 = *(const float4*)&Bs[kk][64 + 4 * tx];
      float a[2][4] = {{A0.x, A0.y, A0.z, A0.w}, {A1.x, A1.y, A1.z, A1.w}};
      float b[2][4] = {{B0.x, B0.y, B0.z, B0.w}, {B1.x, B1.y, B1.z, B1.w}};
#pragma unroll
      for (int ri = 0; ri < 2; ++ri)
#pragma unroll
        for (int i = 0; i < 4; ++i)
#pragma unroll
          for (int ci = 0; ci < 2; ++ci)
#pragma unroll
            for (int j = 0; j < 4; ++j)
              acc[ri][ci][i][j] = fmaf(a[ri][i], b[ci][j], acc[ri][ci][i][j]);
    }
  }
#pragma unroll
  for (int ci = 0; ci < 2; ++ci) {
    float bz[4];
#pragma unroll
    for (int j = 0; j < 4; ++j) bz[j] = bias[n0 + 64 * ci + 4 * tx + j];
#pragma unroll
    for (int ri = 0; ri < 2; ++ri)
#pragma unroll
      for (int i = 0; i < 4; ++i) {
        float4 vv = make_float4(acc[ri][ci][i][0] + bz[0], acc[ri][ci][i][1] + bz[1],
                                acc[ri][ci][i][2] + bz[2], acc[ri][ci][i][3] + bz[3]);
        size_t row = (size_t)b0 * 1024 + m0l + 64 * ri + 4 * ty + i;
        *(float4*)&Out[row * 1024 + n0 + 64 * ci + 4 * tx] = vv;
      }
  }
}

extern "C" void kernel_launch(void* const* d_in, const int* in_sizes, int n_in,
                              void* d_out, int out_size, void* d_ws, size_t ws_size,
                              hipStream_t stream) {
  (void)in_sizes; (void)n_in; (void)out_size;
  const float* x      = (const float*)d_in[0];
  const float* mask   = (const float*)d_in[1];
  const float* W_attn = (const float*)d_in[2];
  const float* b_attn = (const float*)d_in[3];
  const float* W_proj = (const float*)d_in[4];
  const float* b_proj = (const float*)d_in[5];
  float* out = (float*)d_out;

  int CB = (ws_size >= (192ull << 20)) ? 8
         : (ws_size >= (96ull  << 20)) ? 4
         : (ws_size >= (48ull  << 20)) ? 2 : 1;

  char* base = (char*)d_ws;
  double* qT = (double*)base;                                  // CB*8MB
  double* kT = (double*)(base + (size_t)CB * (8ull  << 20));   // CB*8MB
  float*  Vp = (float*)(base + (size_t)CB * (16ull << 20));    // CB*4MB
  float*  AO = (float*)(base + (size_t)CB * (20ull << 20));    // CB*4MB

  for (int b0 = 0; b0 < 8; b0 += CB) {
    qk_gemm_f64<<<dim3(32, 16 * CB), 256, 0, stream>>>(x, W_attn, b_attn, qT, kT, b0);
    v_gemm_f32<<<dim3(8, 8 * CB), 256, 0, stream>>>(x, W_attn, b_attn, Vp, b0);
    attn_fused<<<dim3(16, 16 * CB), 256, 0, stream>>>(qT, kT, Vp, mask, AO, b0);
    proj_gemm<<<dim3(8, 8 * CB), 256, 0, stream>>>(AO, W_proj, b_proj, out, b0);
  }
}